// Round 8
// baseline (729.507 us; speedup 1.0000x reference)
//
#include <hip/hip_runtime.h>
#include <cstddef>
#include <cstdint>

#define BB 8
#define MD 256
#define NP 4096
#define HH 8
#define FF 16
#define SS 32
#define S3 32768
#define CC 152      // H*(F+3)
#define KC 24       // H*3
#define PTS (BB*HH*NP)   // 262144
#define BPT (HH*NP)      // points per batch = 32768
#define BN_CNT (BB*NP)   // 32768
#define EPSV 1e-5f
#define ZSTRH (HH*S3*FF)     // per-batch lattice ushorts (bf16) = 4,194,304 (8 MB)
#define ZCSTR (HH*S3*FF)     // per-batch conv-out floats = 4,194,304 (16 MB)
#define CAPP 576
#define OVFC 256

typedef __attribute__((ext_vector_type(8))) short short8v;
typedef __attribute__((ext_vector_type(4))) float f32x4;

__device__ __forceinline__ unsigned int f2bf(float f) {
    unsigned int u = __float_as_uint(f);
    unsigned int r = u + 0x7FFFu + ((u >> 16) & 1u);   // round-to-nearest-even
    return r >> 16;
}

// ------ GEMM: kv[b,o,n] = sum_m W[o,m] * x[b,m,n]; 32 oc per block ---------
__global__ __launch_bounds__(256) void k_gemm(const float* __restrict__ x,
                                              const float* __restrict__ W,
                                              float* __restrict__ kv) {
    int oc0 = blockIdx.x * 32;          // 5 blocks * 32 = 160 (guard >=152)
    int nt  = blockIdx.y;
    int b   = blockIdx.z;
    int tid = threadIdx.x;
    int n = nt * 256 + tid;

    float acc[32];
#pragma unroll
    for (int r = 0; r < 32; ++r) acc[r] = 0.f;
    const float* xb = x + (size_t)b * MD * NP + n;
#pragma unroll 2
    for (int m = 0; m < MD; ++m) {
        float xv = xb[(size_t)m * NP];
#pragma unroll
        for (int r = 0; r < 32; ++r) {
            int rr = (oc0 + r < CC) ? (oc0 + r) : (CC - 1);
            acc[r] = fmaf(W[(size_t)rr * MD + m], xv, acc[r]);
        }
    }
#pragma unroll
    for (int r = 0; r < 32; ++r)
        if (oc0 + r < CC)
            kv[((size_t)b * CC + oc0 + r) * NP + n] = acc[r];
}

// ------------- BN stats over (B,N) for all 152 kv channels -----------------
__global__ __launch_bounds__(256) void k_stats_kv(const float* __restrict__ kv,
                                                  const float* __restrict__ kg,
                                                  const float* __restrict__ kb,
                                                  const float* __restrict__ vg,
                                                  const float* __restrict__ vb,
                                                  float* __restrict__ A,
                                                  float* __restrict__ Bv) {
    int o = blockIdx.x, tid = threadIdx.x;
    float s = 0.f, ss = 0.f;
    for (int b = 0; b < BB; ++b) {
        const float* p = kv + ((size_t)b * CC + o) * NP;
        for (int n = tid; n < NP; n += 256) { float v = p[n]; s += v; ss = fmaf(v, v, ss); }
    }
#pragma unroll
    for (int off = 32; off > 0; off >>= 1) { s += __shfl_down(s, off); ss += __shfl_down(ss, off); }
    __shared__ float sh[8];
    int lane = tid & 63, w = tid >> 6;
    if (lane == 0) { sh[w] = s; sh[4 + w] = ss; }
    __syncthreads();
    if (tid == 0) {
        float S_ = sh[0] + sh[1] + sh[2] + sh[3];
        float SSv = sh[4] + sh[5] + sh[6] + sh[7];
        float mean = S_ * (1.f / BN_CNT);
        float var  = SSv * (1.f / BN_CNT) - mean * mean;
        float rstd = rsqrtf(var + EPSV);
        float g  = (o < KC) ? kg[o] : vg[o - KC];
        float be = (o < KC) ? kb[o] : vb[o - KC];
        A[o]  = rstd * g;
        Bv[o] = be - mean * rstd * g;
    }
}

// --- per-point: BN keys -> affine -> tanh -> idx/frac; also emit vals[.,16] -
__global__ __launch_bounds__(256) void k_prep(const float* __restrict__ kv,
                                              const float* __restrict__ pcd,
                                              const float* __restrict__ A,
                                              const float* __restrict__ Bv,
                                              const float* __restrict__ R,
                                              const float* __restrict__ t,
                                              int* __restrict__ base,
                                              float* __restrict__ frac,
                                              float* __restrict__ vals) {
    int gid = blockIdx.x * 256 + threadIdx.x;
    int b = gid >> 15, h = (gid >> 12) & 7, n = gid & 4095;

    float p[3];
#pragma unroll
    for (int i = 0; i < 3; ++i) {
        int c = h * 3 + i;
        float v = kv[((size_t)b * CC + c) * NP + n];
        p[i] = pcd[((size_t)b * 3 + i) * NP + n] + fmaf(A[c], v, Bv[c]);
    }
    int fl[3]; float fr[3];
#pragma unroll
    for (int i = 0; i < 3; ++i) {
        float key = R[h * 9 + i * 3 + 0] * p[0] + R[h * 9 + i * 3 + 1] * p[1] +
                    R[h * 9 + i * 3 + 2] * p[2] + t[h * 3 + i];
        float lat = tanhf(key);
        float pos = (lat + 1.f) * 0.5f * (SS - 1);
        float flf = fminf(fmaxf(floorf(pos), 0.f), (float)(SS - 2));
        fr[i] = pos - flf;
        fl[i] = (int)flf;
    }
    base[gid] = (fl[0] * SS + fl[1]) * SS + fl[2];
    frac[gid]           = fr[0];
    frac[PTS + gid]     = fr[1];
    frac[2 * PTS + gid] = fr[2];

    float4* vo = (float4*)(vals + (size_t)gid * 16);
#pragma unroll
    for (int q = 0; q < 4; ++q) {
        float4 v;
        float* vv = (float*)&v;
#pragma unroll
        for (int j = 0; j < 4; ++j) {
            int c = KC + h * FF + q * 4 + j;
            vv[j] = fmaf(A[c], kv[((size_t)b * CC + c) * NP + n], Bv[c]);
        }
        vo[q] = v;
    }
}

// ---- pack conv weights into MFMA A-fragment lane order (bf16) -------------
__global__ __launch_bounds__(256) void k_wpack(const float* __restrict__ cw,
                                               unsigned short* __restrict__ wApack) {
    int gid = blockIdx.x * 256 + threadIdx.x;     // (h*14 + m)*64 + lane
    if (gid >= 8 * 14 * 64) return;
    int lane = gid & 63;
    int m = (gid >> 6) % 14;
    int h = gid / (14 * 64);
    int fo = lane & 15, g = lane >> 4;
    int tap = 2 * m + (g >> 1);
    int ci0 = (g & 1) * 8;
    unsigned short o[8];
#pragma unroll
    for (int j = 0; j < 8; ++j) {
        float w = (tap <= 26) ? cw[((size_t)(h * 16 + fo) * 16 + ci0 + j) * 27 + tap] : 0.f;
        o[j] = (unsigned short)f2bf(w);
    }
    ushort4* dst = (ushort4*)(wApack + (size_t)gid * 8);
    dst[0] = make_ushort4(o[0], o[1], o[2], o[3]);
    dst[1] = make_ushort4(o[4], o[5], o[6], o[7]);
}

// --- splat: block per (x-plane, y-half, h, bq); LDS half-plane + staged pts -
__global__ __launch_bounds__(512) void k_splat(const int* __restrict__ base,
                                               const float* __restrict__ frac,
                                               const float* __restrict__ vals,
                                               unsigned short* __restrict__ zout,
                                               int b0) {
    __shared__ float zl[16][32][16];         // 32 KB fp32 accumulate
    __shared__ int4 pdata[CAPP];             // 9.2 KB staged {p|bs<<12, fx,fy,fz}
    __shared__ unsigned short ovf[OVFC];     // 0.5 KB overflow point ids
    __shared__ int cnt;
    int x  = blockIdx.x;          // 0..31 output plane
    int yh = blockIdx.y;          // 0..1  y half
    int gzb = blockIdx.z;         // h + 8*bq
    int h  = gzb & 7;
    int bq = gzb >> 3;
    int b = b0 + bq;
    int tid = threadIdx.x;

    float4 zero4 = make_float4(0.f, 0.f, 0.f, 0.f);
    float4* zl4 = (float4*)zl;
    for (int i = tid; i < 2048; i += 512) zl4[i] = zero4;
    if (tid == 0) cnt = 0;
    __syncthreads();

    int gb = b * BPT + h * NP;
    for (int p = tid; p < NP; p += 512) {
        int bs = base[gb + p];
        int s = bs >> 10, yl = (bs >> 5) & 31;
        bool xm = (s == x) | (s + 1 == x);
        bool ym = yh ? (yl >= 15) : (yl < 16);
        if (xm && ym) {
            int slot = atomicAdd(&cnt, 1);
            if (slot < CAPP) {
                pdata[slot] = make_int4(p | (bs << 12),
                                        __float_as_int(frac[gb + p]),
                                        __float_as_int(frac[PTS + gb + p]),
                                        __float_as_int(frac[2 * PTS + gb + p]));
            } else if (slot - CAPP < OVFC) {
                ovf[slot - CAPP] = (unsigned short)p;
            }
        }
    }
    __syncthreads();
    int m = min(cnt, CAPP);

    int pl = tid >> 6;            // wave id: one point per wave per pass
    int idx = tid & 63;
    int cor = idx >> 4, ch = idx & 15;
    int dyb = cor >> 1, dzb = cor & 1;
    int yoff = yh * 16;

    for (int i0 = 0; i0 < m; i0 += 16) {
#pragma unroll
        for (int u = 0; u < 2; ++u) {
            int i = i0 + u * 8 + pl;
            if (i < m) {
                int4 pd = pdata[i];
                int p = pd.x & 4095, bs = pd.x >> 12;
                int dxb = x - (bs >> 10);
                int ry = ((bs >> 5) & 31) + dyb - yoff;
                if (ry >= 0 && ry < 16) {
                    float fx = __int_as_float(pd.y), fy = __int_as_float(pd.z),
                          fz = __int_as_float(pd.w);
                    float w = (dxb ? fx : 1.f - fx) * (dyb ? fy : 1.f - fy) *
                              (dzb ? fz : 1.f - fz);
                    float v = vals[(size_t)(gb + p) * 16 + ch];
                    atomicAdd(&zl[ry][(bs & 31) + dzb][ch], w * v);
                }
            }
        }
    }
    // overflow slow path (rare; reads from global)
    int novf = min(cnt - CAPP, OVFC);
    for (int i0 = 0; i0 < novf; i0 += 8) {
        int i = i0 + pl;
        if (i < novf) {
            int p = ovf[i];
            int g = gb + p;
            int bs = base[g];
            int dxb = x - (bs >> 10);
            int ry = ((bs >> 5) & 31) + dyb - yoff;
            if (ry >= 0 && ry < 16) {
                float fx = frac[g], fy = frac[PTS + g], fz = frac[2 * PTS + g];
                float w = (dxb ? fx : 1.f - fx) * (dyb ? fy : 1.f - fy) *
                          (dzb ? fz : 1.f - fz);
                float v = vals[(size_t)g * 16 + ch];
                atomicAdd(&zl[ry][(bs & 31) + dzb][ch], w * v);
            }
        }
    }
    __syncthreads();

    // write half-plane as bf16: 1024 x 16B chunks (8 ch each)
    for (int i = tid; i < 1024; i += 512) {
        int cl = i >> 1, half = i & 1;
        int ry = cl >> 5, zz = cl & 31;
        float4 a = zl4[cl * 4 + half * 2];
        float4 c = zl4[cl * 4 + half * 2 + 1];
        uint4 o;
        o.x = f2bf(a.x) | (f2bf(a.y) << 16);
        o.y = f2bf(a.z) | (f2bf(a.w) << 16);
        o.z = f2bf(c.x) | (f2bf(c.y) << 16);
        o.w = f2bf(c.z) | (f2bf(c.w) << 16);
        int gcell = x * 1024 + (yh * 16 + ry) * 32 + zz;
        *(uint4*)&zout[((size_t)(bq * HH + h) * S3 + gcell) * 16 + half * 8] = o;
    }
}

// ---- grouped 3x3x3 conv via bf16 MFMA; z is bf16 [bq][h][cell][16] --------
__global__ __launch_bounds__(256) void k_conv(const unsigned short* __restrict__ z,
                                              const unsigned short* __restrict__ wApack,
                                              const float* __restrict__ cb,
                                              float* __restrict__ zc) {
    __shared__ __align__(16) unsigned short zl[4][10][34][16];   // 43,520 B
    int bx = blockIdx.x;      // 0..15 -> x pair
    int yq = blockIdx.y;      // 0..3  -> 8 y rows
    int gz = blockIdx.z;      // h + 8*bq
    int h  = gz & 7;
    int bq = gz >> 3;
    int tid = threadIdx.x;
    int lane = tid & 63, wid = tid >> 6;
    int x2 = bx * 2;

    const unsigned short* zb = z + (size_t)bq * ZSTRH;
    float* zcb = zc + (size_t)bq * ZCSTR;

    short8v af[14];
    const short8v* wa = (const short8v*)(wApack + (size_t)h * 14 * 64 * 8);
#pragma unroll
    for (int m = 0; m < 14; ++m) af[m] = wa[m * 64 + lane];

    for (int i = tid; i < 4 * 10 * 34; i += 256) {
        int dxi = i / 340, rem = i % 340;
        int yy = rem / 34, zi = rem % 34;
        int gx = x2 + dxi - 1, gy = yq * 8 + yy - 1, gzz = zi - 1;
        uint4* d4 = (uint4*)(&zl[0][0][0][0] + (size_t)i * 16);
        if (gx >= 0 && gx < SS && gy >= 0 && gy < SS && gzz >= 0 && gzz < SS) {
            const uint4* src = (const uint4*)&zb[((size_t)h * S3 +
                                 (gx * 1024 + gy * 32 + gzz)) * 16];
            d4[0] = src[0];
            d4[1] = src[1];
        } else {
            uint4 zz4 = make_uint4(0, 0, 0, 0);
            d4[0] = zz4; d4[1] = zz4;
        }
    }
    __syncthreads();

    bool lo = (lane & 32) == 0;
    int ci0 = (lane & 16) ? 8 : 0;
    int l15 = lane & 15;
    int fo0 = (lane >> 4) * 4;
    float4 bias = *(const float4*)&cb[h * 16 + fo0];
    const unsigned short* zlf = &zl[0][0][0][0];

#pragma unroll 1
    for (int i = 0; i < 8; ++i) {
        int gi = wid * 8 + i;
        int xl = gi >> 4, yl = (gi >> 1) & 7, zz0 = (gi & 1) * 16;
        int invbase = xl * 340 + yl * 34 + zz0 + l15;

        f32x4 acc = {0.f, 0.f, 0.f, 0.f};
#pragma unroll
        for (int m = 0; m < 14; ++m) {
            const int t0 = 2 * m;
            const int t1 = (2 * m + 1 > 26) ? 26 : (2 * m + 1);
            const int off0 = (t0 / 9) * 340 + ((t0 % 9) / 3) * 34 + (t0 % 3);
            const int off1 = (t1 / 9) * 340 + ((t1 % 9) / 3) * 34 + (t1 % 3);
            int offc = lo ? off0 : off1;
            const short8v* bp = (const short8v*)(zlf + (size_t)(invbase + offc) * 16 + ci0);
            acc = __builtin_amdgcn_mfma_f32_16x16x32_bf16(af[m], *bp, acc, 0, 0, 0);
        }
        int cell = (x2 + xl) * 1024 + (yq * 8 + yl) * 32 + zz0 + l15;
        float4 o;
        o.x = acc[0] + bias.x; o.y = acc[1] + bias.y;
        o.z = acc[2] + bias.z; o.w = acc[3] + bias.w;
        *(float4*)&zcb[((size_t)h * S3 + cell) * 16 + fo0] = o;
    }
}

// --- slice: thread per (point, fo-quad); zc [bq][h][cell][16] --------------
__global__ __launch_bounds__(256) void k_slice(const int* __restrict__ base,
                                               const float* __restrict__ frac,
                                               const float* __restrict__ zc,
                                               float* __restrict__ out, int b0) {
    int lid = blockIdx.x * 256 + threadIdx.x;
    int foq = blockIdx.y;
    int bq = blockIdx.z;
    int b = b0 + bq;
    int h = lid >> 12, n = lid & 4095;
    int gid = b * BPT + lid;
    int bs = base[gid];
    float fx = frac[gid], fy = frac[PTS + gid], fz = frac[2 * PTS + gid];
    float wx[2] = {1.f - fx, fx}, wy[2] = {1.f - fy, fy}, wz[2] = {1.f - fz, fz};
    const float* zb = zc + (size_t)bq * ZCSTR + (size_t)h * S3 * FF + foq * 4;

    float a0 = 0.f, a1 = 0.f, a2 = 0.f, a3 = 0.f;
#pragma unroll
    for (int dx = 0; dx < 2; ++dx)
#pragma unroll
    for (int dy = 0; dy < 2; ++dy)
#pragma unroll
    for (int dz = 0; dz < 2; ++dz) {
        int cell = bs + dx * (SS * SS) + dy * SS + dz;
        float w = wx[dx] * wy[dy] * wz[dz];
        float4 v = *reinterpret_cast<const float4*>(&zb[(size_t)cell * FF]);
        a0 = fmaf(v.x, w, a0); a1 = fmaf(v.y, w, a1);
        a2 = fmaf(v.z, w, a2); a3 = fmaf(v.w, w, a3);
    }
    size_t ob = ((size_t)b * (HH * FF) + h * FF + foq * 4) * NP + n;
    out[ob]          = a0;
    out[ob + NP]     = a1;
    out[ob + 2 * NP] = a2;
    out[ob + 3 * NP] = a3;
}

// ------------- BN stats over (B,N) for the 128 sliced channels -------------
__global__ __launch_bounds__(256) void k_stats2(const float* __restrict__ out,
                                                const float* __restrict__ ag,
                                                const float* __restrict__ ab,
                                                float* __restrict__ A2,
                                                float* __restrict__ B2) {
    int c = blockIdx.x, tid = threadIdx.x;
    float s = 0.f, ss = 0.f;
    for (int b = 0; b < BB; ++b) {
        const float* p = out + ((size_t)b * (HH * FF) + c) * NP;
        for (int n = tid; n < NP; n += 256) { float v = p[n]; s += v; ss = fmaf(v, v, ss); }
    }
#pragma unroll
    for (int off = 32; off > 0; off >>= 1) { s += __shfl_down(s, off); ss += __shfl_down(ss, off); }
    __shared__ float sh[8];
    int lane = tid & 63, w = tid >> 6;
    if (lane == 0) { sh[w] = s; sh[4 + w] = ss; }
    __syncthreads();
    if (tid == 0) {
        float S_ = sh[0] + sh[1] + sh[2] + sh[3];
        float SSv = sh[4] + sh[5] + sh[6] + sh[7];
        float mean = S_ * (1.f / BN_CNT);
        float var  = SSv * (1.f / BN_CNT) - mean * mean;
        float rstd = rsqrtf(var + EPSV);
        A2[c] = rstd * ag[c];
        B2[c] = ab[c] - mean * rstd * ag[c];
    }
}

// ---------------- final BN + ReLU in-place on d_out ------------------------
__global__ __launch_bounds__(256) void k_bnrelu(float* __restrict__ out,
                                                const float* __restrict__ A2,
                                                const float* __restrict__ B2) {
    int gid = blockIdx.x * 256 + threadIdx.x;
    int c = (gid >> 12) & 127;
    float v = out[gid];
    out[gid] = fmaxf(fmaf(A2[c], v, B2[c]), 0.f);
}

// ---------------------------------------------------------------------------
extern "C" void kernel_launch(void* const* d_in, const int* in_sizes, int n_in,
                              void* d_out, int out_size, void* d_ws, size_t ws_size,
                              hipStream_t stream) {
    (void)in_sizes; (void)n_in; (void)out_size;
    const float* x   = (const float*)d_in[0];
    const float* pcd = (const float*)d_in[1];
    const float* W   = (const float*)d_in[2];
    const float* kg  = (const float*)d_in[3];
    const float* kb  = (const float*)d_in[4];
    const float* vg  = (const float*)d_in[5];
    const float* vb  = (const float*)d_in[6];
    const float* R   = (const float*)d_in[7];
    const float* t   = (const float*)d_in[8];
    const float* cw  = (const float*)d_in[9];
    const float* cb  = (const float*)d_in[10];
    const float* ag  = (const float*)d_in[11];
    const float* ab  = (const float*)d_in[12];
    float* out = (float*)d_out;
    char* ws = (char*)d_ws;

    // fixed workspace region (40,898,560 B)
    float* kv   = (float*)(ws + 0);            // 19,922,944; dead after k_prep
    int*   base = (int*)  (ws + 19922944ULL);  //  1,048,576
    float* frac = (float*)(ws + 20971520ULL);  //  3,145,728
    float* A    = (float*)(ws + 24117248ULL);  //  1,024
    float* Bv   = (float*)(ws + 24118272ULL);  //  1,024
    float* A2   = (float*)(ws + 24119296ULL);  //  1,024
    float* B2   = (float*)(ws + 24120320ULL);  //  1,024
    float* vals = (float*)(ws + 24121344ULL);  // 16,777,216 [point][16]
    // wApack in the tail of the dead-after-prep kv region (beyond z bf16 8.4MB)
    unsigned short* wApack = (unsigned short*)(ws + 16777216ULL);

    int NB = 1;
    if (ws_size >= 40898560ULL + 4ULL * (8388608ULL + 16777216ULL))      NB = 4;
    else if (ws_size >= 40898560ULL + 2ULL * (8388608ULL + 16777216ULL)) NB = 2;

    unsigned short* z_bf;
    float* zc;
    if (NB == 1) {
        z_bf = (unsigned short*)kv;             // 8,388,608 B (< wApack offset)
        zc   = (float*)(ws + 40898560ULL);      // 16,777,216 B
    } else {
        z_bf = (unsigned short*)(ws + 40898560ULL);              // NB * 8 MB
        zc   = (float*)(ws + 40898560ULL + (size_t)NB * 8388608ULL);  // NB * 16 MB
    }

    k_gemm<<<dim3(5, 16, BB), 256, 0, stream>>>(x, W, kv);
    k_stats_kv<<<dim3(CC), 256, 0, stream>>>(kv, kg, kb, vg, vb, A, Bv);
    k_prep<<<dim3(PTS / 256), 256, 0, stream>>>(kv, pcd, A, Bv, R, t, base, frac, vals);
    k_wpack<<<dim3(28), 256, 0, stream>>>(cw, wApack);

    for (int b0 = 0; b0 < BB; b0 += NB) {
        k_splat<<<dim3(SS, 2, HH * NB), 512, 0, stream>>>(base, frac, vals, z_bf, b0);
        k_conv<<<dim3(16, 4, HH * NB), 256, 0, stream>>>(z_bf, wApack, cb, zc);
        k_slice<<<dim3(BPT / 256, 4, NB), 256, 0, stream>>>(base, frac, zc, out, b0);
    }

    k_stats2<<<dim3(HH * FF), 256, 0, stream>>>(out, ag, ab, A2, B2);
    k_bnrelu<<<dim3((BB * HH * FF * NP) / 256), 256, 0, stream>>>(out, A2, B2);
}

// Round 9
// 558.490 us; speedup vs baseline: 1.3062x; 1.3062x over previous
//
#include <hip/hip_runtime.h>
#include <cstddef>
#include <cstdint>

#define BB 8
#define MD 256
#define NP 4096
#define HH 8
#define FF 16
#define SS 32
#define S3 32768
#define CC 152      // H*(F+3)
#define KC 24       // H*3
#define PTS (BB*HH*NP)   // 262144
#define BPT (HH*NP)      // points per batch = 32768
#define BN_CNT (BB*NP)   // 32768
#define EPSV 1e-5f
#define ZSTRH (HH*S3*FF)     // per-batch lattice ushorts (bf16) = 4,194,304 (8 MB)
#define ZCSTR (HH*S3*FF)     // per-batch conv-out floats = 4,194,304 (16 MB)
#define CAPP 576
#define OVFC 256

typedef __attribute__((ext_vector_type(8))) short short8v;
typedef __attribute__((ext_vector_type(4))) float f32x4;

__device__ __forceinline__ unsigned int f2bf(float f) {
    unsigned int u = __float_as_uint(f);
    unsigned int r = u + 0x7FFFu + ((u >> 16) & 1u);   // round-to-nearest-even
    return r >> 16;
}

// ---- pack W_kv into MFMA A-fragment lane order (bf16), 10 oc-tiles --------
// frag index: (oct*8 + mc)*64 + lane; lane: oc = oct*16 + (lane&15),
// k = (lane>>4)*8 + j -> m = mc*32 + k
__global__ __launch_bounds__(256) void k_wgpack(const float* __restrict__ W,
                                                unsigned short* __restrict__ wg) {
    int gid = blockIdx.x * 256 + threadIdx.x;     // 10*8*64 = 5120
    if (gid >= 5120) return;
    int lane = gid & 63;
    int mc   = (gid >> 6) & 7;
    int oct  = gid >> 9;
    int oc = oct * 16 + (lane & 15);
    int m0 = mc * 32 + (lane >> 4) * 8;
    unsigned short o[8];
#pragma unroll
    for (int j = 0; j < 8; ++j)
        o[j] = (oc < CC) ? (unsigned short)f2bf(W[(size_t)oc * MD + m0 + j]) : (unsigned short)0;
    ushort4* dst = (ushort4*)(wg + (size_t)gid * 8);
    dst[0] = make_ushort4(o[0], o[1], o[2], o[3]);
    dst[1] = make_ushort4(o[4], o[5], o[6], o[7]);
}

// ------ GEMM via bf16 MFMA: kv[b,o,n] = sum_m W[o,m] x[b,m,n] --------------
// block: 64-n tile x one batch; x staged transposed bf16 in LDS (swizzled)
__global__ __launch_bounds__(256) void k_gemm(const float* __restrict__ x,
                                              const unsigned short* __restrict__ wg,
                                              float* __restrict__ kv) {
    __shared__ __align__(16) unsigned char xl[65536];   // [64 n][256 m] bf16, swz
    int nt = blockIdx.x;          // 0..63
    int b  = blockIdx.y;
    int tid = threadIdx.x;
    int n_l = tid & 63, w = tid >> 6;
    int n0 = nt * 64;

    // stage: wave w covers m === {2w, 2w+1} (mod 8)
    const float* xb = x + (size_t)b * MD * NP + n0;
#pragma unroll 4
    for (int k = 0; k < 32; ++k) {
        int m = k * 8 + w * 2;
        float v0 = xb[(size_t)m * NP + n_l];
        float v1 = xb[(size_t)(m + 1) * NP + n_l];
        unsigned int pk = f2bf(v0) | (f2bf(v1) << 16);
        unsigned int byte = (unsigned)(n_l * 512 + m * 2);
        byte ^= (unsigned)((n_l & 7) << 4);
        *(unsigned int*)(xl + byte) = pk;
    }
    __syncthreads();

    // X-frags: wave w owns n-slice [w*16, w*16+16)
    int lane = tid & 63;
    int nn = w * 16 + (lane & 15);
    int kg = lane >> 4;
    short8v xf[8];
#pragma unroll
    for (int mc = 0; mc < 8; ++mc) {
        unsigned int byte = (unsigned)(nn * 512 + (mc * 32 + kg * 8) * 2);
        byte ^= (unsigned)((nn & 7) << 4);
        xf[mc] = *(const short8v*)(xl + byte);
    }

    f32x4 acc[10];
#pragma unroll
    for (int t = 0; t < 10; ++t) acc[t] = (f32x4){0.f, 0.f, 0.f, 0.f};

    const short8v* wfr = (const short8v*)wg;
#pragma unroll
    for (int oct = 0; oct < 10; ++oct) {
#pragma unroll
        for (int mc = 0; mc < 8; ++mc) {
            short8v wf = wfr[(oct * 8 + mc) * 64 + lane];
            acc[oct] = __builtin_amdgcn_mfma_f32_16x16x32_bf16(wf, xf[mc], acc[oct], 0, 0, 0);
        }
    }

    // store: D col = lane&15 -> n, row = kg*4 + r -> oc
    int n = n0 + nn;
#pragma unroll
    for (int oct = 0; oct < 10; ++oct) {
#pragma unroll
        for (int r = 0; r < 4; ++r) {
            int oc = oct * 16 + kg * 4 + r;
            if (oc < CC)
                kv[((size_t)b * CC + oc) * NP + n] = acc[oct][r];
        }
    }
}

// ------------- BN stats over (B,N) for all 152 kv channels -----------------
__global__ __launch_bounds__(256) void k_stats_kv(const float* __restrict__ kv,
                                                  const float* __restrict__ kg,
                                                  const float* __restrict__ kb,
                                                  const float* __restrict__ vg,
                                                  const float* __restrict__ vb,
                                                  float* __restrict__ A,
                                                  float* __restrict__ Bv) {
    int o = blockIdx.x, tid = threadIdx.x;
    float s = 0.f, ss = 0.f;
    for (int b = 0; b < BB; ++b) {
        const float* p = kv + ((size_t)b * CC + o) * NP;
        for (int n = tid; n < NP; n += 256) { float v = p[n]; s += v; ss = fmaf(v, v, ss); }
    }
#pragma unroll
    for (int off = 32; off > 0; off >>= 1) { s += __shfl_down(s, off); ss += __shfl_down(ss, off); }
    __shared__ float sh[8];
    int lane = tid & 63, w = tid >> 6;
    if (lane == 0) { sh[w] = s; sh[4 + w] = ss; }
    __syncthreads();
    if (tid == 0) {
        float S_ = sh[0] + sh[1] + sh[2] + sh[3];
        float SSv = sh[4] + sh[5] + sh[6] + sh[7];
        float mean = S_ * (1.f / BN_CNT);
        float var  = SSv * (1.f / BN_CNT) - mean * mean;
        float rstd = rsqrtf(var + EPSV);
        float g  = (o < KC) ? kg[o] : vg[o - KC];
        float be = (o < KC) ? kb[o] : vb[o - KC];
        A[o]  = rstd * g;
        Bv[o] = be - mean * rstd * g;
    }
}

// --- per-point: BN keys -> affine -> tanh -> idx/frac; also emit vals[.,16] -
__global__ __launch_bounds__(256) void k_prep(const float* __restrict__ kv,
                                              const float* __restrict__ pcd,
                                              const float* __restrict__ A,
                                              const float* __restrict__ Bv,
                                              const float* __restrict__ R,
                                              const float* __restrict__ t,
                                              int* __restrict__ base,
                                              float* __restrict__ frac,
                                              float* __restrict__ vals) {
    int gid = blockIdx.x * 256 + threadIdx.x;
    int b = gid >> 15, h = (gid >> 12) & 7, n = gid & 4095;

    float p[3];
#pragma unroll
    for (int i = 0; i < 3; ++i) {
        int c = h * 3 + i;
        float v = kv[((size_t)b * CC + c) * NP + n];
        p[i] = pcd[((size_t)b * 3 + i) * NP + n] + fmaf(A[c], v, Bv[c]);
    }
    int fl[3]; float fr[3];
#pragma unroll
    for (int i = 0; i < 3; ++i) {
        float key = R[h * 9 + i * 3 + 0] * p[0] + R[h * 9 + i * 3 + 1] * p[1] +
                    R[h * 9 + i * 3 + 2] * p[2] + t[h * 3 + i];
        float lat = tanhf(key);
        float pos = (lat + 1.f) * 0.5f * (SS - 1);
        float flf = fminf(fmaxf(floorf(pos), 0.f), (float)(SS - 2));
        fr[i] = pos - flf;
        fl[i] = (int)flf;
    }
    base[gid] = (fl[0] * SS + fl[1]) * SS + fl[2];
    frac[gid]           = fr[0];
    frac[PTS + gid]     = fr[1];
    frac[2 * PTS + gid] = fr[2];

    float4* vo = (float4*)(vals + (size_t)gid * 16);
#pragma unroll
    for (int q = 0; q < 4; ++q) {
        float4 v;
        float* vv = (float*)&v;
#pragma unroll
        for (int j = 0; j < 4; ++j) {
            int c = KC + h * FF + q * 4 + j;
            vv[j] = fmaf(A[c], kv[((size_t)b * CC + c) * NP + n], Bv[c]);
        }
        vo[q] = v;
    }
}

// ---- pack conv weights into MFMA A-fragment lane order (bf16) -------------
__global__ __launch_bounds__(256) void k_wpack(const float* __restrict__ cw,
                                               unsigned short* __restrict__ wApack) {
    int gid = blockIdx.x * 256 + threadIdx.x;     // (h*14 + m)*64 + lane
    if (gid >= 8 * 14 * 64) return;
    int lane = gid & 63;
    int m = (gid >> 6) % 14;
    int h = gid / (14 * 64);
    int fo = lane & 15, g = lane >> 4;
    int tap = 2 * m + (g >> 1);
    int ci0 = (g & 1) * 8;
    unsigned short o[8];
#pragma unroll
    for (int j = 0; j < 8; ++j) {
        float w = (tap <= 26) ? cw[((size_t)(h * 16 + fo) * 16 + ci0 + j) * 27 + tap] : 0.f;
        o[j] = (unsigned short)f2bf(w);
    }
    ushort4* dst = (ushort4*)(wApack + (size_t)gid * 8);
    dst[0] = make_ushort4(o[0], o[1], o[2], o[3]);
    dst[1] = make_ushort4(o[4], o[5], o[6], o[7]);
}

// --- splat: block per (x-plane, y-half, h, bq); LDS half-plane + staged pts -
__global__ __launch_bounds__(512) void k_splat(const int* __restrict__ base,
                                               const float* __restrict__ frac,
                                               const float* __restrict__ vals,
                                               unsigned short* __restrict__ zout,
                                               int b0) {
    __shared__ float zl[16][32][16];         // 32 KB fp32 accumulate
    __shared__ int4 pdata[CAPP];             // 9.2 KB staged {p|bs<<12, fx,fy,fz}
    __shared__ unsigned short ovf[OVFC];     // 0.5 KB overflow point ids
    __shared__ int cnt;
    int x  = blockIdx.x;          // 0..31 output plane
    int yh = blockIdx.y;          // 0..1  y half
    int gzb = blockIdx.z;         // h + 8*bq
    int h  = gzb & 7;
    int bq = gzb >> 3;
    int b = b0 + bq;
    int tid = threadIdx.x;

    float4 zero4 = make_float4(0.f, 0.f, 0.f, 0.f);
    float4* zl4 = (float4*)zl;
    for (int i = tid; i < 2048; i += 512) zl4[i] = zero4;
    if (tid == 0) cnt = 0;
    __syncthreads();

    int gb = b * BPT + h * NP;
    for (int p = tid; p < NP; p += 512) {
        int bs = base[gb + p];
        int s = bs >> 10, yl = (bs >> 5) & 31;
        bool xm = (s == x) | (s + 1 == x);
        bool ym = yh ? (yl >= 15) : (yl < 16);
        if (xm && ym) {
            int slot = atomicAdd(&cnt, 1);
            if (slot < CAPP) {
                pdata[slot] = make_int4(p | (bs << 12),
                                        __float_as_int(frac[gb + p]),
                                        __float_as_int(frac[PTS + gb + p]),
                                        __float_as_int(frac[2 * PTS + gb + p]));
            } else if (slot - CAPP < OVFC) {
                ovf[slot - CAPP] = (unsigned short)p;
            }
        }
    }
    __syncthreads();
    int m = min(cnt, CAPP);

    int pl = tid >> 6;            // wave id
    int idx = tid & 63;
    int cor = idx >> 4, ch = idx & 15;
    int dyb = cor >> 1, dzb = cor & 1;
    int yoff = yh * 16;

    for (int i0 = 0; i0 < m; i0 += 32) {   // 4 points in flight per wave
#pragma unroll
        for (int u = 0; u < 4; ++u) {
            int i = i0 + u * 8 + pl;
            if (i < m) {
                int4 pd = pdata[i];
                int p = pd.x & 4095, bs = pd.x >> 12;
                int dxb = x - (bs >> 10);
                int ry = ((bs >> 5) & 31) + dyb - yoff;
                if (ry >= 0 && ry < 16) {
                    float fx = __int_as_float(pd.y), fy = __int_as_float(pd.z),
                          fz = __int_as_float(pd.w);
                    float w = (dxb ? fx : 1.f - fx) * (dyb ? fy : 1.f - fy) *
                              (dzb ? fz : 1.f - fz);
                    float v = vals[(size_t)(gb + p) * 16 + ch];
                    atomicAdd(&zl[ry][(bs & 31) + dzb][ch], w * v);
                }
            }
        }
    }
    // overflow slow path (rare; reads from global)
    int novf = min(cnt - CAPP, OVFC);
    for (int i0 = 0; i0 < novf; i0 += 8) {
        int i = i0 + pl;
        if (i < novf) {
            int p = ovf[i];
            int g = gb + p;
            int bs = base[g];
            int dxb = x - (bs >> 10);
            int ry = ((bs >> 5) & 31) + dyb - yoff;
            if (ry >= 0 && ry < 16) {
                float fx = frac[g], fy = frac[PTS + g], fz = frac[2 * PTS + g];
                float w = (dxb ? fx : 1.f - fx) * (dyb ? fy : 1.f - fy) *
                          (dzb ? fz : 1.f - fz);
                float v = vals[(size_t)g * 16 + ch];
                atomicAdd(&zl[ry][(bs & 31) + dzb][ch], w * v);
            }
        }
    }
    __syncthreads();

    // write half-plane as bf16: 1024 x 16B chunks (8 ch each)
    for (int i = tid; i < 1024; i += 512) {
        int cl = i >> 1, half = i & 1;
        int ry = cl >> 5, zz = cl & 31;
        float4 a = zl4[cl * 4 + half * 2];
        float4 c = zl4[cl * 4 + half * 2 + 1];
        uint4 o;
        o.x = f2bf(a.x) | (f2bf(a.y) << 16);
        o.y = f2bf(a.z) | (f2bf(a.w) << 16);
        o.z = f2bf(c.x) | (f2bf(c.y) << 16);
        o.w = f2bf(c.z) | (f2bf(c.w) << 16);
        int gcell = x * 1024 + (yh * 16 + ry) * 32 + zz;
        *(uint4*)&zout[((size_t)(bq * HH + h) * S3 + gcell) * 16 + half * 8] = o;
    }
}

// ---- grouped 3x3x3 conv via bf16 MFMA; z is bf16 [bq][h][cell][16] --------
__global__ __launch_bounds__(256) void k_conv(const unsigned short* __restrict__ z,
                                              const unsigned short* __restrict__ wApack,
                                              const float* __restrict__ cb,
                                              float* __restrict__ zc) {
    __shared__ __align__(16) unsigned short zl[4][10][34][16];   // 43,520 B
    int bx = blockIdx.x;      // 0..15 -> x pair
    int yq = blockIdx.y;      // 0..3  -> 8 y rows
    int gz = blockIdx.z;      // h + 8*bq
    int h  = gz & 7;
    int bq = gz >> 3;
    int tid = threadIdx.x;
    int lane = tid & 63, wid = tid >> 6;
    int x2 = bx * 2;

    const unsigned short* zb = z + (size_t)bq * ZSTRH;
    float* zcb = zc + (size_t)bq * ZCSTR;

    short8v af[14];
    const short8v* wa = (const short8v*)(wApack + (size_t)h * 14 * 64 * 8);
#pragma unroll
    for (int m = 0; m < 14; ++m) af[m] = wa[m * 64 + lane];

    for (int i = tid; i < 4 * 10 * 34; i += 256) {
        int dxi = i / 340, rem = i % 340;
        int yy = rem / 34, zi = rem % 34;
        int gx = x2 + dxi - 1, gy = yq * 8 + yy - 1, gzz = zi - 1;
        uint4* d4 = (uint4*)(&zl[0][0][0][0] + (size_t)i * 16);
        if (gx >= 0 && gx < SS && gy >= 0 && gy < SS && gzz >= 0 && gzz < SS) {
            const uint4* src = (const uint4*)&zb[((size_t)h * S3 +
                                 (gx * 1024 + gy * 32 + gzz)) * 16];
            d4[0] = src[0];
            d4[1] = src[1];
        } else {
            uint4 zz4 = make_uint4(0, 0, 0, 0);
            d4[0] = zz4; d4[1] = zz4;
        }
    }
    __syncthreads();

    bool lo = (lane & 32) == 0;
    int ci0 = (lane & 16) ? 8 : 0;
    int l15 = lane & 15;
    int fo0 = (lane >> 4) * 4;
    float4 bias = *(const float4*)&cb[h * 16 + fo0];
    const unsigned short* zlf = &zl[0][0][0][0];

#pragma unroll 1
    for (int i = 0; i < 8; ++i) {
        int gi = wid * 8 + i;
        int xl = gi >> 4, yl = (gi >> 1) & 7, zz0 = (gi & 1) * 16;
        int invbase = xl * 340 + yl * 34 + zz0 + l15;

        f32x4 acc = {0.f, 0.f, 0.f, 0.f};
#pragma unroll
        for (int m = 0; m < 14; ++m) {
            const int t0 = 2 * m;
            const int t1 = (2 * m + 1 > 26) ? 26 : (2 * m + 1);
            const int off0 = (t0 / 9) * 340 + ((t0 % 9) / 3) * 34 + (t0 % 3);
            const int off1 = (t1 / 9) * 340 + ((t1 % 9) / 3) * 34 + (t1 % 3);
            int offc = lo ? off0 : off1;
            const short8v* bp = (const short8v*)(zlf + (size_t)(invbase + offc) * 16 + ci0);
            acc = __builtin_amdgcn_mfma_f32_16x16x32_bf16(af[m], *bp, acc, 0, 0, 0);
        }
        int cell = (x2 + xl) * 1024 + (yq * 8 + yl) * 32 + zz0 + l15;
        float4 o;
        o.x = acc[0] + bias.x; o.y = acc[1] + bias.y;
        o.z = acc[2] + bias.z; o.w = acc[3] + bias.w;
        *(float4*)&zcb[((size_t)h * S3 + cell) * 16 + fo0] = o;
    }
}

// --- slice: thread per (point, fo-quad); zc [bq][h][cell][16] --------------
__global__ __launch_bounds__(256) void k_slice(const int* __restrict__ base,
                                               const float* __restrict__ frac,
                                               const float* __restrict__ zc,
                                               float* __restrict__ out, int b0) {
    int lid = blockIdx.x * 256 + threadIdx.x;
    int foq = blockIdx.y;
    int bq = blockIdx.z;
    int b = b0 + bq;
    int h = lid >> 12, n = lid & 4095;
    int gid = b * BPT + lid;
    int bs = base[gid];
    float fx = frac[gid], fy = frac[PTS + gid], fz = frac[2 * PTS + gid];
    float wx[2] = {1.f - fx, fx}, wy[2] = {1.f - fy, fy}, wz[2] = {1.f - fz, fz};
    const float* zb = zc + (size_t)bq * ZCSTR + (size_t)h * S3 * FF + foq * 4;

    float a0 = 0.f, a1 = 0.f, a2 = 0.f, a3 = 0.f;
#pragma unroll
    for (int dx = 0; dx < 2; ++dx)
#pragma unroll
    for (int dy = 0; dy < 2; ++dy)
#pragma unroll
    for (int dz = 0; dz < 2; ++dz) {
        int cell = bs + dx * (SS * SS) + dy * SS + dz;
        float w = wx[dx] * wy[dy] * wz[dz];
        float4 v = *reinterpret_cast<const float4*>(&zb[(size_t)cell * FF]);
        a0 = fmaf(v.x, w, a0); a1 = fmaf(v.y, w, a1);
        a2 = fmaf(v.z, w, a2); a3 = fmaf(v.w, w, a3);
    }
    size_t ob = ((size_t)b * (HH * FF) + h * FF + foq * 4) * NP + n;
    out[ob]          = a0;
    out[ob + NP]     = a1;
    out[ob + 2 * NP] = a2;
    out[ob + 3 * NP] = a3;
}

// ------------- BN stats over (B,N) for the 128 sliced channels -------------
__global__ __launch_bounds__(256) void k_stats2(const float* __restrict__ out,
                                                const float* __restrict__ ag,
                                                const float* __restrict__ ab,
                                                float* __restrict__ A2,
                                                float* __restrict__ B2) {
    int c = blockIdx.x, tid = threadIdx.x;
    float s = 0.f, ss = 0.f;
    for (int b = 0; b < BB; ++b) {
        const float* p = out + ((size_t)b * (HH * FF) + c) * NP;
        for (int n = tid; n < NP; n += 256) { float v = p[n]; s += v; ss = fmaf(v, v, ss); }
    }
#pragma unroll
    for (int off = 32; off > 0; off >>= 1) { s += __shfl_down(s, off); ss += __shfl_down(ss, off); }
    __shared__ float sh[8];
    int lane = tid & 63, w = tid >> 6;
    if (lane == 0) { sh[w] = s; sh[4 + w] = ss; }
    __syncthreads();
    if (tid == 0) {
        float S_ = sh[0] + sh[1] + sh[2] + sh[3];
        float SSv = sh[4] + sh[5] + sh[6] + sh[7];
        float mean = S_ * (1.f / BN_CNT);
        float var  = SSv * (1.f / BN_CNT) - mean * mean;
        float rstd = rsqrtf(var + EPSV);
        A2[c] = rstd * ag[c];
        B2[c] = ab[c] - mean * rstd * ag[c];
    }
}

// ---------------- final BN + ReLU in-place on d_out ------------------------
__global__ __launch_bounds__(256) void k_bnrelu(float* __restrict__ out,
                                                const float* __restrict__ A2,
                                                const float* __restrict__ B2) {
    int gid = blockIdx.x * 256 + threadIdx.x;
    int c = (gid >> 12) & 127;
    float v = out[gid];
    out[gid] = fmaxf(fmaf(A2[c], v, B2[c]), 0.f);
}

// ---------------------------------------------------------------------------
extern "C" void kernel_launch(void* const* d_in, const int* in_sizes, int n_in,
                              void* d_out, int out_size, void* d_ws, size_t ws_size,
                              hipStream_t stream) {
    (void)in_sizes; (void)n_in; (void)out_size;
    const float* x   = (const float*)d_in[0];
    const float* pcd = (const float*)d_in[1];
    const float* W   = (const float*)d_in[2];
    const float* kg  = (const float*)d_in[3];
    const float* kb  = (const float*)d_in[4];
    const float* vg  = (const float*)d_in[5];
    const float* vb  = (const float*)d_in[6];
    const float* R   = (const float*)d_in[7];
    const float* t   = (const float*)d_in[8];
    const float* cw  = (const float*)d_in[9];
    const float* cb  = (const float*)d_in[10];
    const float* ag  = (const float*)d_in[11];
    const float* ab  = (const float*)d_in[12];
    float* out = (float*)d_out;
    char* ws = (char*)d_ws;

    // fixed workspace region (40,898,560 B)
    float* kv   = (float*)(ws + 0);            // 19,922,944; dead after k_prep
    int*   base = (int*)  (ws + 19922944ULL);  //  1,048,576
    float* frac = (float*)(ws + 20971520ULL);  //  3,145,728
    float* A    = (float*)(ws + 24117248ULL);  //  1,024
    float* Bv   = (float*)(ws + 24118272ULL);  //  1,024
    float* A2   = (float*)(ws + 24119296ULL);  //  1,024
    float* B2   = (float*)(ws + 24120320ULL);  //  1,024
    float* vals = (float*)(ws + 24121344ULL);  // 16,777,216 [point][16]
    // conv wApack in the tail of the dead-after-prep kv region
    unsigned short* wApack = (unsigned short*)(ws + 16777216ULL);

    int NB = 1;
    if (ws_size >= 40898560ULL + 4ULL * (8388608ULL + 16777216ULL))      NB = 4;
    else if (ws_size >= 40898560ULL + 2ULL * (8388608ULL + 16777216ULL)) NB = 2;

    unsigned short* z_bf;
    float* zc;
    if (NB == 1) {
        z_bf = (unsigned short*)kv;             // 8,388,608 B (< wApack offset)
        zc   = (float*)(ws + 40898560ULL);      // 16,777,216 B
    } else {
        z_bf = (unsigned short*)(ws + 40898560ULL);              // NB * 8 MB
        zc   = (float*)(ws + 40898560ULL + (size_t)NB * 8388608ULL);  // NB * 16 MB
    }
    // GEMM W-pack (80 KB) aliases the zc region: written before k_gemm,
    // read only by k_gemm, clobbered later by k_conv.
    unsigned short* wg = (unsigned short*)zc;

    k_wgpack<<<dim3(20), 256, 0, stream>>>(W, wg);
    k_gemm<<<dim3(64, BB), 256, 0, stream>>>(x, wg, kv);
    k_stats_kv<<<dim3(CC), 256, 0, stream>>>(kv, kg, kb, vg, vb, A, Bv);
    k_prep<<<dim3(PTS / 256), 256, 0, stream>>>(kv, pcd, A, Bv, R, t, base, frac, vals);
    k_wpack<<<dim3(28), 256, 0, stream>>>(cw, wApack);

    for (int b0 = 0; b0 < BB; b0 += NB) {
        k_splat<<<dim3(SS, 2, HH * NB), 512, 0, stream>>>(base, frac, vals, z_bf, b0);
        k_conv<<<dim3(16, 4, HH * NB), 256, 0, stream>>>(z_bf, wApack, cb, zc);
        k_slice<<<dim3(BPT / 256, 4, NB), 256, 0, stream>>>(base, frac, zc, out, b0);
    }

    k_stats2<<<dim3(HH * FF), 256, 0, stream>>>(out, ag, ab, A2, B2);
    k_bnrelu<<<dim3((BB * HH * FF * NP) / 256), 256, 0, stream>>>(out, A2, B2);
}